// Round 3
// baseline (736.340 us; speedup 1.0000x reference)
//
#include <hip/hip_runtime.h>

// MoE top-2 layer, MI355X — round 3: pipelined K-loop (AITER-style).
// Double-buffered LDS, raw s_barrier + manual s_waitcnt vmcnt(4) so next
// iteration's global_load_lds stays in flight across the barrier (prefetch
// survives; __syncthreads would drain vmcnt(0) and expose full load latency).
//
// All GEMM operands pre-packed fp16 [kb][row][32] so each 128x32 tile is one
// contiguous 8KB block -> global_load_lds width=16 for BOTH operands.
// N=4096 tokens, C=1024, E=8, H=4096, top-2. NPC=9216 slot capacity.

#define NTOK  4096
#define CDIM  1024
#define HDIM  4096
#define NEXP  8
#define NPC   9216
#define MAXMT 72
#define KB_C  32     // CDIM/32
#define KB_H  128    // HDIM/32

typedef _Float16 half8 __attribute__((ext_vector_type(8)));
typedef float    f32x4 __attribute__((ext_vector_type(4)));

// async global->LDS, 16B per lane. LDS dest = wave-uniform base + lane*16.
#define ASYNC_CP16(gp, lp)                                                         \
  __builtin_amdgcn_global_load_lds(                                                \
      (const __attribute__((address_space(1))) unsigned int*)(gp),                 \
      (__attribute__((address_space(3))) unsigned int*)(lp), 16, 0, 0)

#define BAR()     asm volatile("s_barrier" ::: "memory")
#define WAITVM4() asm volatile("s_waitcnt vmcnt(4)" ::: "memory")
#define WAITVM0() asm volatile("s_waitcnt vmcnt(0)" ::: "memory")

__device__ __forceinline__ float gelu_new(float x) {
    const float c = 0.7978845608028654f;  // sqrt(2/pi)
    return 0.5f * x * (1.0f + tanhf(c * (x + 0.044715f * x * x * x)));
}

// ---------------- utility ----------------

__global__ void zero_u32(unsigned int* __restrict__ p, int n) {
    int i = blockIdx.x * 256 + threadIdx.x;
    if (i < n) p[i] = 0u;
}

__global__ void zero_meta(unsigned int* __restrict__ pt, unsigned int* __restrict__ pg,
                          unsigned int* __restrict__ cnt) {
    int i = blockIdx.x * 256 + threadIdx.x;
    if (i < NPC) { pt[i] = 0u; pg[i] = 0u; }
    if (i < NEXP) cnt[i] = 0u;
}

// ---------------- routing ----------------

__global__ __launch_bounds__(256) void router_kernel(
    const float* __restrict__ x, const float* __restrict__ rw,
    int* __restrict__ tok_e, float* __restrict__ tok_w, int* __restrict__ counts)
{
    int wave = threadIdx.x >> 6, lane = threadIdx.x & 63;
    int n = blockIdx.x * 4 + wave;
    const float* xr = x + (size_t)n * CDIM;
    float acc[NEXP];
    #pragma unroll
    for (int e = 0; e < NEXP; ++e) acc[e] = 0.f;
    for (int c = lane; c < CDIM; c += 64) {
        float xv = xr[c];
        #pragma unroll
        for (int e = 0; e < NEXP; ++e) acc[e] = fmaf(xv, rw[e * CDIM + c], acc[e]);
    }
    #pragma unroll
    for (int e = 0; e < NEXP; ++e) {
        float v = acc[e];
        #pragma unroll
        for (int off = 32; off > 0; off >>= 1) v += __shfl_down(v, off);
        acc[e] = v;
    }
    if (lane == 0) {
        float l0 = -3.0e38f, l1 = -3.0e38f; int b0 = 0, b1 = 0;
        #pragma unroll
        for (int e = 0; e < NEXP; ++e) {
            float v = acc[e];
            if (v > l0)      { l1 = l0; b1 = b0; l0 = v; b0 = e; }
            else if (v > l1) { l1 = v; b1 = e; }
        }
        float t  = expf(l1 - l0);            // l1 <= l0, stable
        float w0 = 1.f / (1.f + t);
        float w1 = t  / (1.f + t);
        tok_e[n * 2]     = b0;  tok_e[n * 2 + 1] = b1;
        tok_w[n * 2]     = w0;  tok_w[n * 2 + 1] = w1;
        atomicAdd(&counts[b0], 1);
        atomicAdd(&counts[b1], 1);
    }
}

__global__ void plan_kernel(const int* __restrict__ counts, int* __restrict__ cursors,
                            int* __restrict__ mtiles, int* __restrict__ tile_expert)
{
    if (threadIdx.x == 0 && blockIdx.x == 0) {
        int b = 0;
        for (int e = 0; e < NEXP; ++e) {
            cursors[e] = b;
            int tiles = (counts[e] + 127) >> 7;
            for (int t = 0; t < tiles; ++t) tile_expert[(b >> 7) + t] = e;
            b += tiles << 7;
        }
        *mtiles = b >> 7;
        for (int t = b >> 7; t < MAXMT; ++t) tile_expert[t] = 0;
    }
}

__global__ void assign_kernel(const int* __restrict__ tok_e, const float* __restrict__ tok_w,
                              int* __restrict__ cursors,
                              int* __restrict__ pair_tok, float* __restrict__ pair_gate)
{
    int n = blockIdx.x * 256 + threadIdx.x;  // exactly NTOK threads
    #pragma unroll
    for (int k = 0; k < 2; ++k) {
        int e = tok_e[n * 2 + k];
        int slot = atomicAdd(&cursors[e], 1);
        pair_tok[slot]  = n;
        pair_gate[slot] = tok_w[n * 2 + k];
    }
}

// ---------------- A gather+convert into packed layout ----------------

__global__ __launch_bounds__(256) void gather_x_kernel(
    const float* __restrict__ x, const int* __restrict__ pair_tok,
    _Float16* __restrict__ xg)
{
    int o = blockIdx.x * 256 + threadIdx.x;          // KB_C * NPC * 4 threads
    int kb   = o / (NPC * 4);
    int rem  = o - kb * (NPC * 4);
    int slot = rem >> 2;
    int c    = (rem & 3) * 8;
    int tok  = pair_tok[slot];
    const float* src = x + (size_t)tok * CDIM + kb * 32 + c;
    float4 a = *(const float4*)src;
    float4 b = *(const float4*)(src + 4);
    half8 h;
    h[0] = (_Float16)a.x; h[1] = (_Float16)a.y; h[2] = (_Float16)a.z; h[3] = (_Float16)a.w;
    h[4] = (_Float16)b.x; h[5] = (_Float16)b.y; h[6] = (_Float16)b.z; h[7] = (_Float16)b.w;
    *(half8*)(xg + ((size_t)kb * NPC + slot) * 32 + c) = h;
}

// ---------------- weight transpose+convert ----------------
// w [E][K][N] fp32 -> wt [E][K/32][N][32] fp16

__global__ __launch_bounds__(256) void transpose_cvt_kernel(
    const float* __restrict__ w, _Float16* __restrict__ wt, int K, int N)
{
    __shared__ float tile[32][68];
    const int e = blockIdx.z, k0 = blockIdx.y * 32, n0 = blockIdx.x * 64;
    const float* src = w + ((size_t)e * K + k0) * N + n0;
    const int t = threadIdx.x;
    #pragma unroll
    for (int f = t; f < 512; f += 256) {
        int k = f >> 4, nc = (f & 15) * 4;
        *(float4*)&tile[k][nc] = *(const float4*)(src + (size_t)k * N + nc);
    }
    __syncthreads();
    int n = t >> 2, c2 = (t & 3) * 8;
    half8 h;
    #pragma unroll
    for (int q = 0; q < 8; ++q) h[q] = (_Float16)tile[c2 + q][n];
    int KB = K >> 5;
    _Float16* dst = wt + (((size_t)e * KB + (k0 >> 5)) * N + (n0 + n)) * 32 + c2;
    *(half8*)dst = h;
}

// ---------------- GEMM 1: hb = gelu(xg @ wt_fc + b_fc) ----------------
// 128x128 tile, BK=32, 2-stage pipelined LDS, 4 waves x (4x4 16x16x32 mfma).

__global__ __launch_bounds__(256, 4) void gemm_fc_kernel(
    const _Float16* __restrict__ xg,     // packed [KB_C][NPC][32]
    const _Float16* __restrict__ wt,     // packed [E][KB_C][HDIM][32]
    const float*    __restrict__ b_fc,   // [E][HDIM]
    const int*      __restrict__ tile_expert,
    const int*      __restrict__ mtiles,
    _Float16*       __restrict__ hb)     // packed [KB_H][NPC][32]
{
    const int mt = blockIdx.y;
    if (mt >= *mtiles) return;
    const int nt = blockIdx.x;
    const int e  = tile_expert[mt];
    const int m0 = mt << 7, n0 = nt << 7;

    __shared__ _Float16 As[2][128 * 32];
    __shared__ _Float16 Bs[2][128 * 32];

    const int tid = threadIdx.x;
    const int lane = tid & 63, wv = tid >> 6;
    const int wm = (wv >> 1) * 64, wn = (wv & 1) * 64;
    const int l16 = lane & 15, lq = lane >> 4;

    const char* gA0 = (const char*)xg + (size_t)m0 * 64;
    const char* gB0 = (const char*)wt + ((size_t)e * KB_C * HDIM + n0) * 64;
    const int soff = wv * 2048 + lane * 16;
    char* lA0 = (char*)As[0] + wv * 2048;  char* lA1 = (char*)As[1] + wv * 2048;
    char* lB0 = (char*)Bs[0] + wv * 2048;  char* lB1 = (char*)Bs[1] + wv * 2048;

    f32x4 acc[4][4];
    #pragma unroll
    for (int i = 0; i < 4; ++i)
        #pragma unroll
        for (int j = 0; j < 4; ++j) { acc[i][j][0]=0.f; acc[i][j][1]=0.f; acc[i][j][2]=0.f; acc[i][j][3]=0.f; }

    auto issue = [&](char* lA, char* lB, int kb) {
        const char* ga = gA0 + (size_t)kb * (NPC * 64) + soff;
        const char* gb = gB0 + (size_t)kb * (HDIM * 64) + soff;
        ASYNC_CP16(ga,        lA);
        ASYNC_CP16(ga + 1024, lA + 1024);
        ASYNC_CP16(gb,        lB);
        ASYNC_CP16(gb + 1024, lB + 1024);
    };
    auto compute = [&](const _Float16* Ab, const _Float16* Bb) {
        half8 af[4], bfv[4];
        #pragma unroll
        for (int i = 0; i < 4; ++i) af[i]  = *(const half8*)&Ab[(wm + i * 16 + l16) * 32 + lq * 8];
        #pragma unroll
        for (int j = 0; j < 4; ++j) bfv[j] = *(const half8*)&Bb[(wn + j * 16 + l16) * 32 + lq * 8];
        #pragma unroll
        for (int i = 0; i < 4; ++i)
            #pragma unroll
            for (int j = 0; j < 4; ++j)
                acc[i][j] = __builtin_amdgcn_mfma_f32_16x16x32_f16(af[i], bfv[j], acc[i][j], 0, 0, 0);
    };

    issue(lA0, lB0, 0);
    for (int kb = 0; kb < KB_C; kb += 2) {
        if (kb + 1 < KB_C) { issue(lA1, lB1, kb + 1); WAITVM4(); } else { WAITVM0(); }
        BAR();
        compute(As[0], Bs[0]);
        BAR();
        if (kb + 2 < KB_C) { issue(lA0, lB0, kb + 2); WAITVM4(); } else { WAITVM0(); }
        BAR();
        compute(As[1], Bs[1]);
        BAR();
    }

    float bias[4];
    #pragma unroll
    for (int j = 0; j < 4; ++j) bias[j] = b_fc[e * HDIM + n0 + wn + j * 16 + l16];
    #pragma unroll
    for (int i = 0; i < 4; ++i) {
        #pragma unroll
        for (int r = 0; r < 4; ++r) {
            int slot = m0 + wm + i * 16 + lq * 4 + r;   // D row = quad*4 + reg
            #pragma unroll
            for (int j = 0; j < 4; ++j) {
                int n = n0 + wn + j * 16 + l16;          // D col = lane&15
                float v = gelu_new(acc[i][j][r] + bias[j]);
                hb[((size_t)(n >> 5) * NPC + slot) * 32 + (n & 31)] = (_Float16)v;
            }
        }
    }
}

// ---------------- GEMM 2: y[tok] += gate * (hb @ wt_proj + b_proj), split-K=2 ----------------

__global__ __launch_bounds__(256, 4) void gemm_proj_kernel(
    const _Float16* __restrict__ hb,     // packed [KB_H][NPC][32]
    const _Float16* __restrict__ wt,     // packed [E][KB_H][CDIM][32]
    const float*    __restrict__ b_proj, // [E][CDIM]
    const int*      __restrict__ pair_tok,
    const float*    __restrict__ pair_gate,
    const int*      __restrict__ tile_expert,
    const int*      __restrict__ mtiles,
    float*          __restrict__ y)      // [NTOK][CDIM]
{
    const int mt = blockIdx.y;
    if (mt >= *mtiles) return;
    const int nt = blockIdx.x;
    const int ks = blockIdx.z;           // kb in [ks*64, ks*64+64)
    const int e  = tile_expert[mt];
    const int m0 = mt << 7, n0 = nt << 7;

    __shared__ _Float16 As[2][128 * 32];
    __shared__ _Float16 Bs[2][128 * 32];

    const int tid = threadIdx.x;
    const int lane = tid & 63, wv = tid >> 6;
    const int wm = (wv >> 1) * 64, wn = (wv & 1) * 64;
    const int l16 = lane & 15, lq = lane >> 4;

    const char* gA0 = (const char*)hb + (size_t)m0 * 64;
    const char* gB0 = (const char*)wt + ((size_t)e * KB_H * CDIM + n0) * 64;
    const int soff = wv * 2048 + lane * 16;
    char* lA0 = (char*)As[0] + wv * 2048;  char* lA1 = (char*)As[1] + wv * 2048;
    char* lB0 = (char*)Bs[0] + wv * 2048;  char* lB1 = (char*)Bs[1] + wv * 2048;

    f32x4 acc[4][4];
    #pragma unroll
    for (int i = 0; i < 4; ++i)
        #pragma unroll
        for (int j = 0; j < 4; ++j) { acc[i][j][0]=0.f; acc[i][j][1]=0.f; acc[i][j][2]=0.f; acc[i][j][3]=0.f; }

    auto issue = [&](char* lA, char* lB, int kb) {
        const char* ga = gA0 + (size_t)kb * (NPC * 64) + soff;
        const char* gb = gB0 + (size_t)kb * (CDIM * 64) + soff;
        ASYNC_CP16(ga,        lA);
        ASYNC_CP16(ga + 1024, lA + 1024);
        ASYNC_CP16(gb,        lB);
        ASYNC_CP16(gb + 1024, lB + 1024);
    };
    auto compute = [&](const _Float16* Ab, const _Float16* Bb) {
        half8 af[4], bfv[4];
        #pragma unroll
        for (int i = 0; i < 4; ++i) af[i]  = *(const half8*)&Ab[(wm + i * 16 + l16) * 32 + lq * 8];
        #pragma unroll
        for (int j = 0; j < 4; ++j) bfv[j] = *(const half8*)&Bb[(wn + j * 16 + l16) * 32 + lq * 8];
        #pragma unroll
        for (int i = 0; i < 4; ++i)
            #pragma unroll
            for (int j = 0; j < 4; ++j)
                acc[i][j] = __builtin_amdgcn_mfma_f32_16x16x32_f16(af[i], bfv[j], acc[i][j], 0, 0, 0);
    };

    const int kbeg = ks * 64, kend = kbeg + 64;
    issue(lA0, lB0, kbeg);
    for (int kb = kbeg; kb < kend; kb += 2) {
        if (kb + 1 < kend) { issue(lA1, lB1, kb + 1); WAITVM4(); } else { WAITVM0(); }
        BAR();
        compute(As[0], Bs[0]);
        BAR();
        if (kb + 2 < kend) { issue(lA0, lB0, kb + 2); WAITVM4(); } else { WAITVM0(); }
        BAR();
        compute(As[1], Bs[1]);
        BAR();
    }

    float bias[4];
    #pragma unroll
    for (int j = 0; j < 4; ++j)
        bias[j] = (ks == 0) ? b_proj[e * CDIM + n0 + wn + j * 16 + l16] : 0.0f;
    #pragma unroll
    for (int i = 0; i < 4; ++i) {
        #pragma unroll
        for (int r = 0; r < 4; ++r) {
            int slot = m0 + wm + i * 16 + lq * 4 + r;
            float g  = pair_gate[slot];
            if (g != 0.0f) {
                int tok = pair_tok[slot];
                float* dst = y + (size_t)tok * CDIM + n0 + wn + l16;
                #pragma unroll
                for (int j = 0; j < 4; ++j)
                    atomicAdd(&dst[j * 16], (acc[i][j][r] + bias[j]) * g);
            }
        }
    }
}

// ---------------- launch ----------------

extern "C" void kernel_launch(void* const* d_in, const int* in_sizes, int n_in,
                              void* d_out, int out_size, void* d_ws, size_t ws_size,
                              hipStream_t stream) {
    const float* x   = (const float*)d_in[0];
    const float* rw  = (const float*)d_in[1];
    const float* wfc = (const float*)d_in[2];
    const float* bfc = (const float*)d_in[3];
    const float* wpj = (const float*)d_in[4];
    const float* bpj = (const float*)d_in[5];
    float* y = (float*)d_out;

    char* ws = (char*)d_ws;
    // workspace layout (bytes), total ~161.7 MB
    _Float16* xg  = (_Float16*)(ws);                    // 18,874,368  [KB_C][NPC][32]
    _Float16* hb  = (_Float16*)(ws + 18874368);         // 75,497,472  [KB_H][NPC][32]
    _Float16* wt  = (_Float16*)(ws + 94371840);         // 67,108,864  shared fc/proj
    char* meta = ws + 161480704;
    int*   pair_tok    = (int*)  (meta);                //  36,864
    float* pair_gate   = (float*)(meta + 36864);        //  36,864
    int*   tok_e       = (int*)  (meta + 73728);        //  32,768
    float* tok_w       = (float*)(meta + 106496);       //  32,768
    int*   counts      = (int*)  (meta + 139264);       // 8
    int*   cursors     = counts + 8;                    // 8
    int*   mtiles      = cursors + 8;                   // 1 (+pad)
    int*   tile_expert = mtiles + 2;                    // 72

    zero_meta<<<36, 256, 0, stream>>>((unsigned int*)pair_tok, (unsigned int*)pair_gate,
                                      (unsigned int*)counts);
    zero_u32<<<16384, 256, 0, stream>>>((unsigned int*)y, NTOK * CDIM);

    router_kernel<<<1024, 256, 0, stream>>>(x, rw, tok_e, tok_w, counts);
    plan_kernel<<<1, 64, 0, stream>>>(counts, cursors, mtiles, tile_expert);
    assign_kernel<<<16, 256, 0, stream>>>(tok_e, tok_w, cursors, pair_tok, pair_gate);
    gather_x_kernel<<<KB_C * NPC * 4 / 256, 256, 0, stream>>>(x, pair_tok, xg);

    // fc: transpose w_fc -> wt, then GEMM into hb
    transpose_cvt_kernel<<<dim3(HDIM / 64, CDIM / 32, NEXP), 256, 0, stream>>>(wfc, wt, CDIM, HDIM);
    gemm_fc_kernel<<<dim3(HDIM / 128, MAXMT), 256, 0, stream>>>(
        xg, wt, bfc, tile_expert, mtiles, hb);

    // proj: transpose w_proj -> wt (reuse buffer), then GEMM into y
    transpose_cvt_kernel<<<dim3(CDIM / 64, HDIM / 32, NEXP), 256, 0, stream>>>(wpj, wt, HDIM, CDIM);
    gemm_proj_kernel<<<dim3(CDIM / 128, MAXMT, 2), 256, 0, stream>>>(
        hb, wt, bpj, pair_tok, pair_gate, tile_expert, mtiles, y);
}